// Round 3
// baseline (148.401 us; speedup 1.0000x reference)
//
#include <hip/hip_runtime.h>
#include <hip/hip_bf16.h>
#include <stdint.h>

// Problem constants (B=8, S=512, D=1024)
constexpr int N_TOK  = 4096;   // B*S
constexpr int D_DIM  = 1024;
constexpr int MASK_ID_V = 8192;

// Fast-path tiling: 128x128 tiles, 32x32 grid, CTS=1
constexpr int BM   = 128;
constexpr int BN   = 128;
constexpr int BK   = 64;
constexpr int NSL  = N_TOK / BN;     // 32 column slices
constexpr int KST  = D_DIM / BK;     // 16 K-steps
constexpr int NPART = NSL * 2;       // 64 partials/row (2 wc-waves per slice)

// Fallback tiling (round-2 kernel, used only if ws too small)
constexpr int NSLICE_FB = 8;
constexpr int SLICE_W   = N_TOK / NSLICE_FB;   // 512
constexpr int CTS       = SLICE_W / BN;        // 4
constexpr int LDW       = BK + 8;              // padded row for fallback
constexpr int NPART_FB  = NSLICE_FB * 2;       // 16

typedef __attribute__((ext_vector_type(4))) float f32x4;
typedef __attribute__((ext_vector_type(8))) short bf16x8;

__device__ __forceinline__ uint32_t pk2bf(float lo, float hi) {
    // round-to-nearest-even fp32 -> bf16, packed pair
    union { float f; uint32_t u; } a, b;
    a.f = lo; b.f = hi;
    uint32_t ua = (a.u + 0x7fffu + ((a.u >> 16) & 1u)) >> 16;
    uint32_t ub = (b.u + 0x7fffu + ((b.u >> 16) & 1u)) >> 16;
    return ua | (ub << 16);
}

// async global->LDS, 16B per lane; LDS dest must be wave-uniform base (+lane*16 by HW)
__device__ __forceinline__ void async16(void* lds, const void* g) {
    __builtin_amdgcn_global_load_lds(
        (const __attribute__((address_space(1))) uint32_t*)g,
        (__attribute__((address_space(3))) uint32_t*)lds,
        16, 0, 0);
}

// ---------------------------------------------------------------------------
// Pass 1: fp32 -> bf16 pre-convert (once, instead of 16x redundant in-loop)
// ---------------------------------------------------------------------------
__global__ __launch_bounds__(256) void conv_bf16(
    const float* __restrict__ x, const float* __restrict__ e,
    ushort* __restrict__ xb, ushort* __restrict__ eb)
{
    constexpr int NCHUNK = N_TOK * D_DIM / 8;   // 524288 chunks of 8 elems
    const int t0 = blockIdx.x * blockDim.x + threadIdx.x;
    const int stride = gridDim.x * blockDim.x;
    for (int c = t0; c < NCHUNK; c += stride) {
        float4 a0 = ((const float4*)x)[c * 2];
        float4 a1 = ((const float4*)x)[c * 2 + 1];
        uint4 p;
        p.x = pk2bf(a0.x, a0.y); p.y = pk2bf(a0.z, a0.w);
        p.z = pk2bf(a1.x, a1.y); p.w = pk2bf(a1.z, a1.w);
        ((uint4*)xb)[c] = p;

        float4 b0 = ((const float4*)e)[c * 2];
        float4 b1 = ((const float4*)e)[c * 2 + 1];
        uint4 q;
        q.x = pk2bf(b0.x, b0.y); q.y = pk2bf(b0.z, b0.w);
        q.z = pk2bf(b1.x, b1.y); q.w = pk2bf(b1.z, b1.w);
        ((uint4*)eb)[c] = q;
    }
}

// ---------------------------------------------------------------------------
// Pass 2: scores tile GEMM (bf16 MFMA, global_load_lds staging) + online lse
// ---------------------------------------------------------------------------
__global__ __launch_bounds__(256, 4) void nce_gemm2(
    const ushort* __restrict__ xb,    // [N_TOK, D] bf16 keys
    const ushort* __restrict__ eb,    // [N_TOK, D] bf16 queries
    float* __restrict__ numer,        // [N_TOK]
    float* __restrict__ pm,           // [N_TOK, NPART]
    float* __restrict__ ps)           // [N_TOK, NPART]
{
    __shared__ ushort At[BM][BK];     // 16 KB, linear (global_load_lds dest)
    __shared__ ushort Bt[BN][BK];     // 16 KB

    const int rb   = blockIdx.x;      // 0..31 row block
    const int cs   = blockIdx.y;      // 0..31 col slice
    const int row0 = rb * BM;
    const int col0 = cs * BN;

    const int tid  = threadIdx.x;
    const int lane = tid & 63;
    const int wid  = tid >> 6;
    const int wr   = wid >> 1;        // 0..1
    const int wc   = wid & 1;         // 0..1
    const int l15  = lane & 15;
    const int lhi  = lane >> 4;       // 0..3

    f32x4 acc[4][4];
#pragma unroll
    for (int a = 0; a < 4; ++a)
#pragma unroll
        for (int b = 0; b < 4; ++b)
            acc[a][b] = f32x4{0.f, 0.f, 0.f, 0.f};

#pragma unroll 1
    for (int kt = 0; kt < KST; ++kt) {
        __syncthreads();              // previous iter's readers done
        // Stage A (eb rows) and B (xb rows): 16KB each = 16 wave-instrs, 4/wave
#pragma unroll
        for (int j = 0; j < 4; ++j) {
            const int q0 = (wid * 4 + j) * 64;   // first 16B-chunk this instr
            const int ca = q0 + lane;            // this lane's chunk
            const int r  = ca >> 3;              // 8 chunks per 64-elem row
            const int c8 = (ca & 7) << 3;
            async16((char*)At + (size_t)q0 * 16,
                    eb + (size_t)(row0 + r) * D_DIM + kt * BK + c8);
            async16((char*)Bt + (size_t)q0 * 16,
                    xb + (size_t)(col0 + r) * D_DIM + kt * BK + c8);
        }
        __syncthreads();              // drains vmcnt before reads

#pragma unroll
        for (int kp = 0; kp < 2; ++kp) {
            const int ko = kp * 32 + lhi * 8;
            bf16x8 af[4], bfr[4];
#pragma unroll
            for (int mi = 0; mi < 4; ++mi)
                af[mi] = *(const bf16x8*)&At[wr * 64 + mi * 16 + l15][ko];
#pragma unroll
            for (int ni = 0; ni < 4; ++ni)
                bfr[ni] = *(const bf16x8*)&Bt[wc * 64 + ni * 16 + l15][ko];
#pragma unroll
            for (int mi = 0; mi < 4; ++mi)
#pragma unroll
                for (int ni = 0; ni < 4; ++ni)
                    acc[mi][ni] = __builtin_amdgcn_mfma_f32_16x16x32_bf16(
                        af[mi], bfr[ni], acc[mi][ni], 0, 0, 0);
        }
    }

    // Epilogue: diagonal + per-lane (m,s) + 16-lane butterfly + partial write
    float m_l[16], s_l[16];
#pragma unroll
    for (int mi = 0; mi < 4; ++mi)
#pragma unroll
        for (int r = 0; r < 4; ++r) {
            const int idx   = mi * 4 + r;
            const int row_g = row0 + wr * 64 + mi * 16 + lhi * 4 + r;
#pragma unroll
            for (int ni = 0; ni < 4; ++ni) {
                const int col_g = col0 + wc * 64 + ni * 16 + l15;
                if (row_g == col_g) numer[row_g] = acc[mi][ni][r];
            }
            const float v0 = acc[mi][0][r], v1 = acc[mi][1][r];
            const float v2 = acc[mi][2][r], v3 = acc[mi][3][r];
            const float mx = fmaxf(fmaxf(v0, v1), fmaxf(v2, v3));
            m_l[idx] = mx;
            s_l[idx] = __expf(v0 - mx) + __expf(v1 - mx)
                     + __expf(v2 - mx) + __expf(v3 - mx);
        }

#pragma unroll
    for (int idx = 0; idx < 16; ++idx) {
        float m = m_l[idx], s = s_l[idx];
#pragma unroll
        for (int off = 1; off < 16; off <<= 1) {
            const float mo = __shfl_xor(m, off, 64);
            const float so = __shfl_xor(s, off, 64);
            const float mn = fmaxf(m, mo);
            s = s * __expf(m - mn) + so * __expf(mo - mn);
            m = mn;
        }
        m_l[idx] = m; s_l[idx] = s;
    }

    if (l15 == 0) {
        const int slot = cs * 2 + wc;
#pragma unroll
        for (int mi = 0; mi < 4; ++mi)
#pragma unroll
            for (int r = 0; r < 4; ++r) {
                const int row_g = row0 + wr * 64 + mi * 16 + lhi * 4 + r;
                pm[row_g * NPART + slot] = m_l[mi * 4 + r];
                ps[row_g * NPART + slot] = s_l[mi * 4 + r];
            }
    }
}

// ---------------------------------------------------------------------------
// Pass 3: combine partials -> lse, masked mean, scalar
// ---------------------------------------------------------------------------
__global__ void nce_finish(
    const int* __restrict__ tgt,
    const float* __restrict__ numer,
    const float* __restrict__ pm,
    const float* __restrict__ ps,
    float* __restrict__ out,
    int npart)
{
    const int tid = threadIdx.x;   // 1 block
    const int nt  = blockDim.x;
    float loss = 0.f, cnt = 0.f;

    for (int row = tid; row < N_TOK; row += nt) {
        if (tgt[row] != MASK_ID_V) continue;
        float m = -3.0e38f;
        for (int k = 0; k < npart; ++k) m = fmaxf(m, pm[row * npart + k]);
        float s = 0.f;
        for (int k = 0; k < npart; ++k)
            s += ps[row * npart + k] * __expf(pm[row * npart + k] - m);
        loss += numer[row] - (m + __logf(s));
        cnt  += 1.f;
    }

    __shared__ float sl[1024], sc[1024];
    sl[tid] = loss; sc[tid] = cnt;
    __syncthreads();
    for (int off = nt >> 1; off > 0; off >>= 1) {
        if (tid < off) { sl[tid] += sl[tid + off]; sc[tid] += sc[tid + off]; }
        __syncthreads();
    }
    if (tid == 0) out[0] = -(sl[0] / sc[0]);
}

// ---------------------------------------------------------------------------
// Fallback (round-2 kernel): on-the-fly convert, used only if ws too small
// ---------------------------------------------------------------------------
__global__ __launch_bounds__(256, 2) void nce_gemm_fb(
    const float* __restrict__ x, const float* __restrict__ emb,
    float* __restrict__ numer, float* __restrict__ pm, float* __restrict__ ps)
{
    __shared__ ushort At[BM][LDW];
    __shared__ ushort Bt[BN][LDW];

    const int rb = blockIdx.x, cs = blockIdx.y;
    const int row0 = rb * BM, col0 = cs * SLICE_W;
    const int tid = threadIdx.x, lane = tid & 63, wid = tid >> 6;
    const int wr = wid >> 1, wc = wid & 1, l15 = lane & 15, lhi = lane >> 4;

    float m_run[16], s_run[16];
#pragma unroll
    for (int i = 0; i < 16; ++i) { m_run[i] = -3.0e38f; s_run[i] = 0.0f; }

    for (int ct = 0; ct < CTS; ++ct) {
        const int colt0 = col0 + ct * BN;
        f32x4 acc[4][4];
#pragma unroll
        for (int a = 0; a < 4; ++a)
#pragma unroll
            for (int b = 0; b < 4; ++b) acc[a][b] = f32x4{0.f,0.f,0.f,0.f};

#pragma unroll 1
        for (int kt = 0; kt < KST; ++kt) {
            __syncthreads();
#pragma unroll
            for (int i = 0; i < 4; ++i) {
                const int chunk = tid + i * 256;
                const int r = chunk >> 3, c8 = (chunk & 7) << 3;
                const float* ga = emb + (size_t)(row0 + r) * D_DIM + kt * BK + c8;
                float4 a0 = *(const float4*)(ga); float4 a1 = *(const float4*)(ga + 4);
                uint4 pa;
                pa.x = pk2bf(a0.x, a0.y); pa.y = pk2bf(a0.z, a0.w);
                pa.z = pk2bf(a1.x, a1.y); pa.w = pk2bf(a1.z, a1.w);
                *(uint4*)&At[r][c8] = pa;
                const float* gb = x + (size_t)(colt0 + r) * D_DIM + kt * BK + c8;
                float4 b0 = *(const float4*)(gb); float4 b1 = *(const float4*)(gb + 4);
                uint4 pb;
                pb.x = pk2bf(b0.x, b0.y); pb.y = pk2bf(b0.z, b0.w);
                pb.z = pk2bf(b1.x, b1.y); pb.w = pk2bf(b1.z, b1.w);
                *(uint4*)&Bt[r][c8] = pb;
            }
            __syncthreads();
#pragma unroll
            for (int kp = 0; kp < 2; ++kp) {
                const int ko = kp * 32 + lhi * 8;
                bf16x8 af[4], bfr[4];
#pragma unroll
                for (int mi = 0; mi < 4; ++mi)
                    af[mi] = *(const bf16x8*)&At[wr*64 + mi*16 + l15][ko];
#pragma unroll
                for (int ni = 0; ni < 4; ++ni)
                    bfr[ni] = *(const bf16x8*)&Bt[wc*64 + ni*16 + l15][ko];
#pragma unroll
                for (int mi = 0; mi < 4; ++mi)
#pragma unroll
                    for (int ni = 0; ni < 4; ++ni)
                        acc[mi][ni] = __builtin_amdgcn_mfma_f32_16x16x32_bf16(
                            af[mi], bfr[ni], acc[mi][ni], 0, 0, 0);
            }
        }

#pragma unroll
        for (int mi = 0; mi < 4; ++mi)
#pragma unroll
            for (int r = 0; r < 4; ++r) {
                const int row_g = row0 + wr*64 + mi*16 + lhi*4 + r;
#pragma unroll
                for (int ni = 0; ni < 4; ++ni) {
                    const int col_g = colt0 + wc*64 + ni*16 + l15;
                    if (row_g == col_g) numer[row_g] = acc[mi][ni][r];
                }
                const int idx = mi * 4 + r;
                const float v0 = acc[mi][0][r], v1 = acc[mi][1][r];
                const float v2 = acc[mi][2][r], v3 = acc[mi][3][r];
                const float mx = fmaxf(fmaxf(v0, v1), fmaxf(v2, v3));
                const float mn = fmaxf(m_run[idx], mx);
                const float scale = __expf(m_run[idx] - mn);
                s_run[idx] = s_run[idx] * scale
                           + __expf(v0 - mn) + __expf(v1 - mn)
                           + __expf(v2 - mn) + __expf(v3 - mn);
                m_run[idx] = mn;
            }
    }

#pragma unroll
    for (int idx = 0; idx < 16; ++idx) {
        float m = m_run[idx], s = s_run[idx];
#pragma unroll
        for (int off = 1; off < 16; off <<= 1) {
            const float mo = __shfl_xor(m, off, 64);
            const float so = __shfl_xor(s, off, 64);
            const float mn = fmaxf(m, mo);
            s = s * __expf(m - mn) + so * __expf(mo - mn);
            m = mn;
        }
        m_run[idx] = m; s_run[idx] = s;
    }

    if (l15 == 0) {
        const int slot = cs * 2 + wc;
#pragma unroll
        for (int mi = 0; mi < 4; ++mi)
#pragma unroll
            for (int r = 0; r < 4; ++r) {
                const int row_g = row0 + wr*64 + mi*16 + lhi*4 + r;
                pm[row_g * NPART_FB + slot] = m_run[mi*4 + r];
                ps[row_g * NPART_FB + slot] = s_run[mi*4 + r];
            }
    }
}

extern "C" void kernel_launch(void* const* d_in, const int* in_sizes, int n_in,
                              void* d_out, int out_size, void* d_ws, size_t ws_size,
                              hipStream_t stream) {
    (void)in_sizes; (void)n_in; (void)out_size;
    const float* x   = (const float*)d_in[0];
    const float* emb = (const float*)d_in[1];
    const int*   tgt = (const int*)d_in[2];
    float* out = (float*)d_out;

    const size_t elems = (size_t)N_TOK * D_DIM;
    const size_t need  = elems * 2 * 2            // xb + eb (bf16)
                       + (size_t)N_TOK * 4        // numer
                       + (size_t)N_TOK * NPART * 4 * 2;  // pm + ps

    if (ws_size >= need) {
        ushort* xb    = (ushort*)d_ws;
        ushort* eb    = xb + elems;
        float*  numer = (float*)(eb + elems);
        float*  pm    = numer + N_TOK;
        float*  ps    = pm + (size_t)N_TOK * NPART;

        conv_bf16<<<1024, 256, 0, stream>>>(x, emb, xb, eb);
        nce_gemm2<<<dim3(N_TOK / BM, NSL), 256, 0, stream>>>(xb, eb, numer, pm, ps);
        nce_finish<<<1, 1024, 0, stream>>>(tgt, numer, pm, ps, out, NPART);
    } else {
        float* numer = (float*)d_ws;
        float* pm    = numer + N_TOK;
        float* ps    = pm + (size_t)N_TOK * NPART_FB;
        nce_gemm_fb<<<dim3(N_TOK / BM, NSLICE_FB), 256, 0, stream>>>(x, emb, numer, pm, ps);
        nce_finish<<<1, 1024, 0, stream>>>(tgt, numer, pm, ps, out, NPART_FB);
    }
}

// Round 4
// 65.707 us; speedup vs baseline: 2.2585x; 2.2585x over previous
//
#include <hip/hip_runtime.h>
#include <hip/hip_bf16.h>
#include <stdint.h>

// Problem constants (B=8, S=512, D=1024)
constexpr int N_TOK  = 4096;   // B*S
constexpr int D_DIM  = 1024;
constexpr int MASK_ID_V = 8192;

// Fast-path tiling: 128x128 tiles, 32x32 grid
constexpr int BM   = 128;
constexpr int BN   = 128;
constexpr int BK   = 64;
constexpr int NSL  = N_TOK / BN;     // 32 column slices
constexpr int KST  = D_DIM / BK;     // 16 K-steps
constexpr int NPART = NSL * 2;       // 64 partials/row (2 wc-waves per slice)

// Fallback tiling (used only if ws too small)
constexpr int NSLICE_FB = 8;
constexpr int SLICE_W   = N_TOK / NSLICE_FB;   // 512
constexpr int CTS       = SLICE_W / BN;        // 4
constexpr int LDW       = BK + 8;
constexpr int NPART_FB  = NSLICE_FB * 2;       // 16

constexpr int FIN_BLOCKS = 256;      // finish_a grid

typedef __attribute__((ext_vector_type(4))) float f32x4;
typedef __attribute__((ext_vector_type(8))) short bf16x8;

__device__ __forceinline__ uint32_t pk2bf(float lo, float hi) {
    union { float f; uint32_t u; } a, b;
    a.f = lo; b.f = hi;
    uint32_t ua = (a.u + 0x7fffu + ((a.u >> 16) & 1u)) >> 16;
    uint32_t ub = (b.u + 0x7fffu + ((b.u >> 16) & 1u)) >> 16;
    return ua | (ub << 16);
}

__device__ __forceinline__ void async16(void* lds, const void* g) {
    __builtin_amdgcn_global_load_lds(
        (const __attribute__((address_space(1))) uint32_t*)g,
        (__attribute__((address_space(3))) uint32_t*)lds,
        16, 0, 0);
}

// ---------------------------------------------------------------------------
// Pass 1: fp32 -> bf16 pre-convert (once)
// ---------------------------------------------------------------------------
__global__ __launch_bounds__(256) void conv_bf16(
    const float* __restrict__ x, const float* __restrict__ e,
    ushort* __restrict__ xb, ushort* __restrict__ eb)
{
    constexpr int NCHUNK = N_TOK * D_DIM / 8;
    const int t0 = blockIdx.x * blockDim.x + threadIdx.x;
    const int stride = gridDim.x * blockDim.x;
    for (int c = t0; c < NCHUNK; c += stride) {
        float4 a0 = ((const float4*)x)[c * 2];
        float4 a1 = ((const float4*)x)[c * 2 + 1];
        uint4 p;
        p.x = pk2bf(a0.x, a0.y); p.y = pk2bf(a0.z, a0.w);
        p.z = pk2bf(a1.x, a1.y); p.w = pk2bf(a1.z, a1.w);
        ((uint4*)xb)[c] = p;

        float4 b0 = ((const float4*)e)[c * 2];
        float4 b1 = ((const float4*)e)[c * 2 + 1];
        uint4 q;
        q.x = pk2bf(b0.x, b0.y); q.y = pk2bf(b0.z, b0.w);
        q.z = pk2bf(b1.x, b1.y); q.w = pk2bf(b1.z, b1.w);
        ((uint4*)eb)[c] = q;
    }
}

// ---------------------------------------------------------------------------
// Pass 2: scores tile GEMM (bf16 MFMA, global_load_lds staging) + online lse
// ---------------------------------------------------------------------------
__global__ __launch_bounds__(256, 4) void nce_gemm2(
    const ushort* __restrict__ xb,
    const ushort* __restrict__ eb,
    float* __restrict__ numer,
    float* __restrict__ pm,
    float* __restrict__ ps)
{
    __shared__ ushort At[BM][BK];
    __shared__ ushort Bt[BN][BK];

    const int rb   = blockIdx.x;
    const int cs   = blockIdx.y;
    const int row0 = rb * BM;
    const int col0 = cs * BN;

    const int tid  = threadIdx.x;
    const int lane = tid & 63;
    const int wid  = tid >> 6;
    const int wr   = wid >> 1;
    const int wc   = wid & 1;
    const int l15  = lane & 15;
    const int lhi  = lane >> 4;

    f32x4 acc[4][4];
#pragma unroll
    for (int a = 0; a < 4; ++a)
#pragma unroll
        for (int b = 0; b < 4; ++b)
            acc[a][b] = f32x4{0.f, 0.f, 0.f, 0.f};

#pragma unroll 1
    for (int kt = 0; kt < KST; ++kt) {
        __syncthreads();
#pragma unroll
        for (int j = 0; j < 4; ++j) {
            const int q0 = (wid * 4 + j) * 64;
            const int ca = q0 + lane;
            const int r  = ca >> 3;
            const int c8 = (ca & 7) << 3;
            async16((char*)At + (size_t)q0 * 16,
                    eb + (size_t)(row0 + r) * D_DIM + kt * BK + c8);
            async16((char*)Bt + (size_t)q0 * 16,
                    xb + (size_t)(col0 + r) * D_DIM + kt * BK + c8);
        }
        __syncthreads();

#pragma unroll
        for (int kp = 0; kp < 2; ++kp) {
            const int ko = kp * 32 + lhi * 8;
            bf16x8 af[4], bfr[4];
#pragma unroll
            for (int mi = 0; mi < 4; ++mi)
                af[mi] = *(const bf16x8*)&At[wr * 64 + mi * 16 + l15][ko];
#pragma unroll
            for (int ni = 0; ni < 4; ++ni)
                bfr[ni] = *(const bf16x8*)&Bt[wc * 64 + ni * 16 + l15][ko];
#pragma unroll
            for (int mi = 0; mi < 4; ++mi)
#pragma unroll
                for (int ni = 0; ni < 4; ++ni)
                    acc[mi][ni] = __builtin_amdgcn_mfma_f32_16x16x32_bf16(
                        af[mi], bfr[ni], acc[mi][ni], 0, 0, 0);
        }
    }

    float m_l[16], s_l[16];
#pragma unroll
    for (int mi = 0; mi < 4; ++mi)
#pragma unroll
        for (int r = 0; r < 4; ++r) {
            const int idx   = mi * 4 + r;
            const int row_g = row0 + wr * 64 + mi * 16 + lhi * 4 + r;
#pragma unroll
            for (int ni = 0; ni < 4; ++ni) {
                const int col_g = col0 + wc * 64 + ni * 16 + l15;
                if (row_g == col_g) numer[row_g] = acc[mi][ni][r];
            }
            const float v0 = acc[mi][0][r], v1 = acc[mi][1][r];
            const float v2 = acc[mi][2][r], v3 = acc[mi][3][r];
            const float mx = fmaxf(fmaxf(v0, v1), fmaxf(v2, v3));
            m_l[idx] = mx;
            s_l[idx] = __expf(v0 - mx) + __expf(v1 - mx)
                     + __expf(v2 - mx) + __expf(v3 - mx);
        }

#pragma unroll
    for (int idx = 0; idx < 16; ++idx) {
        float m = m_l[idx], s = s_l[idx];
#pragma unroll
        for (int off = 1; off < 16; off <<= 1) {
            const float mo = __shfl_xor(m, off, 64);
            const float so = __shfl_xor(s, off, 64);
            const float mn = fmaxf(m, mo);
            s = s * __expf(m - mn) + so * __expf(mo - mn);
            m = mn;
        }
        m_l[idx] = m; s_l[idx] = s;
    }

    if (l15 == 0) {
        const int slot = cs * 2 + wc;
#pragma unroll
        for (int mi = 0; mi < 4; ++mi)
#pragma unroll
            for (int r = 0; r < 4; ++r) {
                const int row_g = row0 + wr * 64 + mi * 16 + lhi * 4 + r;
                pm[row_g * NPART + slot] = m_l[mi * 4 + r];
                ps[row_g * NPART + slot] = s_l[mi * 4 + r];
            }
    }
}

// ---------------------------------------------------------------------------
// Pass 3a: one WAVE per row — coalesced partial combine + masked row loss
// ---------------------------------------------------------------------------
__global__ __launch_bounds__(256) void nce_finish_a(
    const int* __restrict__ tgt,
    const float* __restrict__ numer,
    const float* __restrict__ pm,
    const float* __restrict__ ps,
    float* __restrict__ bl_loss,
    float* __restrict__ bl_cnt,
    int npart)
{
    const int tid  = threadIdx.x;
    const int lane = tid & 63;
    const int wv   = tid >> 6;                  // 0..3
    const int waves_total = gridDim.x * 4;

    float loss = 0.f, cnt = 0.f;

    for (int row = blockIdx.x * 4 + wv; row < N_TOK; row += waves_total) {
        if (tgt[row] != MASK_ID_V) continue;    // wave-uniform branch
        float pmv = -3.0e38f, psv = 0.f;
        if (lane < npart) {
            pmv = pm[row * npart + lane];
            psv = ps[row * npart + lane];
        }
        float m = pmv;
#pragma unroll
        for (int off = 32; off; off >>= 1) m = fmaxf(m, __shfl_xor(m, off, 64));
        float sv = psv * __expf(pmv - m);       // inactive lanes: 0 * e^{-inf} = 0
#pragma unroll
        for (int off = 32; off; off >>= 1) sv += __shfl_xor(sv, off, 64);
        if (lane == 0) {
            loss += numer[row] - (m + __logf(sv));
            cnt  += 1.f;
        }
    }

    __shared__ float sl[4], sc[4];
    if (lane == 0) { sl[wv] = loss; sc[wv] = cnt; }
    __syncthreads();
    if (tid == 0) {
        bl_loss[blockIdx.x] = sl[0] + sl[1] + sl[2] + sl[3];
        bl_cnt[blockIdx.x]  = sc[0] + sc[1] + sc[2] + sc[3];
    }
}

// ---------------------------------------------------------------------------
// Pass 3b: combine block partials -> scalar
// ---------------------------------------------------------------------------
__global__ __launch_bounds__(256) void nce_finish_b(
    const float* __restrict__ bl_loss,
    const float* __restrict__ bl_cnt,
    float* __restrict__ out, int nblk)
{
    const int tid = threadIdx.x;                // 256 threads, 1 block
    float l = 0.f, c = 0.f;
    for (int i = tid; i < nblk; i += 256) { l += bl_loss[i]; c += bl_cnt[i]; }
    __shared__ float sl[256], sc[256];
    sl[tid] = l; sc[tid] = c;
    __syncthreads();
    for (int off = 128; off; off >>= 1) {
        if (tid < off) { sl[tid] += sl[tid + off]; sc[tid] += sc[tid + off]; }
        __syncthreads();
    }
    if (tid == 0) out[0] = -(sl[0] / sc[0]);
}

// ---------------------------------------------------------------------------
// Fallback (on-the-fly convert) — only if ws too small
// ---------------------------------------------------------------------------
__global__ __launch_bounds__(256, 2) void nce_gemm_fb(
    const float* __restrict__ x, const float* __restrict__ emb,
    float* __restrict__ numer, float* __restrict__ pm, float* __restrict__ ps)
{
    __shared__ ushort At[BM][LDW];
    __shared__ ushort Bt[BN][LDW];

    const int rb = blockIdx.x, cs = blockIdx.y;
    const int row0 = rb * BM, col0 = cs * SLICE_W;
    const int tid = threadIdx.x, lane = tid & 63, wid = tid >> 6;
    const int wr = wid >> 1, wc = wid & 1, l15 = lane & 15, lhi = lane >> 4;

    float m_run[16], s_run[16];
#pragma unroll
    for (int i = 0; i < 16; ++i) { m_run[i] = -3.0e38f; s_run[i] = 0.0f; }

    for (int ct = 0; ct < CTS; ++ct) {
        const int colt0 = col0 + ct * BN;
        f32x4 acc[4][4];
#pragma unroll
        for (int a = 0; a < 4; ++a)
#pragma unroll
            for (int b = 0; b < 4; ++b) acc[a][b] = f32x4{0.f,0.f,0.f,0.f};

#pragma unroll 1
        for (int kt = 0; kt < KST; ++kt) {
            __syncthreads();
#pragma unroll
            for (int i = 0; i < 4; ++i) {
                const int chunk = tid + i * 256;
                const int r = chunk >> 3, c8 = (chunk & 7) << 3;
                const float* ga = emb + (size_t)(row0 + r) * D_DIM + kt * BK + c8;
                float4 a0 = *(const float4*)(ga); float4 a1 = *(const float4*)(ga + 4);
                uint4 pa;
                pa.x = pk2bf(a0.x, a0.y); pa.y = pk2bf(a0.z, a0.w);
                pa.z = pk2bf(a1.x, a1.y); pa.w = pk2bf(a1.z, a1.w);
                *(uint4*)&At[r][c8] = pa;
                const float* gb = x + (size_t)(colt0 + r) * D_DIM + kt * BK + c8;
                float4 b0 = *(const float4*)(gb); float4 b1 = *(const float4*)(gb + 4);
                uint4 pb;
                pb.x = pk2bf(b0.x, b0.y); pb.y = pk2bf(b0.z, b0.w);
                pb.z = pk2bf(b1.x, b1.y); pb.w = pk2bf(b1.z, b1.w);
                *(uint4*)&Bt[r][c8] = pb;
            }
            __syncthreads();
#pragma unroll
            for (int kp = 0; kp < 2; ++kp) {
                const int ko = kp * 32 + lhi * 8;
                bf16x8 af[4], bfr[4];
#pragma unroll
                for (int mi = 0; mi < 4; ++mi)
                    af[mi] = *(const bf16x8*)&At[wr*64 + mi*16 + l15][ko];
#pragma unroll
                for (int ni = 0; ni < 4; ++ni)
                    bfr[ni] = *(const bf16x8*)&Bt[wc*64 + ni*16 + l15][ko];
#pragma unroll
                for (int mi = 0; mi < 4; ++mi)
#pragma unroll
                    for (int ni = 0; ni < 4; ++ni)
                        acc[mi][ni] = __builtin_amdgcn_mfma_f32_16x16x32_bf16(
                            af[mi], bfr[ni], acc[mi][ni], 0, 0, 0);
            }
        }

#pragma unroll
        for (int mi = 0; mi < 4; ++mi)
#pragma unroll
            for (int r = 0; r < 4; ++r) {
                const int row_g = row0 + wr*64 + mi*16 + lhi*4 + r;
#pragma unroll
                for (int ni = 0; ni < 4; ++ni) {
                    const int col_g = colt0 + wc*64 + ni*16 + l15;
                    if (row_g == col_g) numer[row_g] = acc[mi][ni][r];
                }
                const int idx = mi * 4 + r;
                const float v0 = acc[mi][0][r], v1 = acc[mi][1][r];
                const float v2 = acc[mi][2][r], v3 = acc[mi][3][r];
                const float mx = fmaxf(fmaxf(v0, v1), fmaxf(v2, v3));
                const float mn = fmaxf(m_run[idx], mx);
                const float scale = __expf(m_run[idx] - mn);
                s_run[idx] = s_run[idx] * scale
                           + __expf(v0 - mn) + __expf(v1 - mn)
                           + __expf(v2 - mn) + __expf(v3 - mn);
                m_run[idx] = mn;
            }
    }

#pragma unroll
    for (int idx = 0; idx < 16; ++idx) {
        float m = m_run[idx], s = s_run[idx];
#pragma unroll
        for (int off = 1; off < 16; off <<= 1) {
            const float mo = __shfl_xor(m, off, 64);
            const float so = __shfl_xor(s, off, 64);
            const float mn = fmaxf(m, mo);
            s = s * __expf(m - mn) + so * __expf(mo - mn);
            m = mn;
        }
        m_run[idx] = m; s_run[idx] = s;
    }

    if (l15 == 0) {
        const int slot = cs * 2 + wc;
#pragma unroll
        for (int mi = 0; mi < 4; ++mi)
#pragma unroll
            for (int r = 0; r < 4; ++r) {
                const int row_g = row0 + wr*64 + mi*16 + lhi*4 + r;
                pm[row_g * NPART_FB + slot] = m_run[mi*4 + r];
                ps[row_g * NPART_FB + slot] = s_run[mi*4 + r];
            }
    }
}

extern "C" void kernel_launch(void* const* d_in, const int* in_sizes, int n_in,
                              void* d_out, int out_size, void* d_ws, size_t ws_size,
                              hipStream_t stream) {
    (void)in_sizes; (void)n_in; (void)out_size;
    const float* x   = (const float*)d_in[0];
    const float* emb = (const float*)d_in[1];
    const int*   tgt = (const int*)d_in[2];
    float* out = (float*)d_out;

    const size_t elems = (size_t)N_TOK * D_DIM;
    const size_t need  = elems * 2 * 2
                       + (size_t)N_TOK * 4
                       + (size_t)N_TOK * NPART * 4 * 2
                       + FIN_BLOCKS * 8;

    if (ws_size >= need) {
        ushort* xb    = (ushort*)d_ws;
        ushort* eb    = xb + elems;
        float*  numer = (float*)(eb + elems);
        float*  pm    = numer + N_TOK;
        float*  ps    = pm + (size_t)N_TOK * NPART;
        float*  bl    = ps + (size_t)N_TOK * NPART;   // [FIN_BLOCKS] loss
        float*  bc    = bl + FIN_BLOCKS;              // [FIN_BLOCKS] cnt

        conv_bf16<<<1024, 256, 0, stream>>>(x, emb, xb, eb);
        nce_gemm2<<<dim3(N_TOK / BM, NSL), 256, 0, stream>>>(xb, eb, numer, pm, ps);
        nce_finish_a<<<FIN_BLOCKS, 256, 0, stream>>>(tgt, numer, pm, ps, bl, bc, NPART);
        nce_finish_b<<<1, 256, 0, stream>>>(bl, bc, out, FIN_BLOCKS);
    } else {
        float* numer = (float*)d_ws;
        float* pm    = numer + N_TOK;
        float* ps    = pm + (size_t)N_TOK * NPART_FB;
        float* bl    = ps + (size_t)N_TOK * NPART_FB;
        float* bc    = bl + FIN_BLOCKS;
        nce_gemm_fb<<<dim3(N_TOK / BM, NSLICE_FB), 256, 0, stream>>>(x, emb, numer, pm, ps);
        nce_finish_a<<<FIN_BLOCKS, 256, 0, stream>>>(tgt, numer, pm, ps, bl, bc, NPART_FB);
        nce_finish_b<<<1, 256, 0, stream>>>(bl, bc, out, FIN_BLOCKS);
    }
}

// Round 5
// 60.331 us; speedup vs baseline: 2.4598x; 1.0891x over previous
//
#include <hip/hip_runtime.h>
#include <hip/hip_bf16.h>
#include <stdint.h>

// Problem constants (B=8, S=512, D=1024)
constexpr int N_TOK  = 4096;   // B*S
constexpr int D_DIM  = 1024;
constexpr int MASK_ID_V = 8192;

// 8-phase fast path: 256x256 tiles, 16x16 grid, BK=64 (2 halves of 32)
constexpr int BM2  = 256;
constexpr int KT2  = D_DIM / 64;     // 16 K-tiles
constexpr int NSL2 = N_TOK / BM2;    // 16 col slices
constexpr int NPART = NSL2 * 4;      // 64 partials/row (4 wc-waves per slice)

// Fallback tiling (used only if ws too small): round-2 on-the-fly kernel
constexpr int BM = 128, BN = 128, BK = 64;
constexpr int KST = D_DIM / BK;
constexpr int NSLICE_FB = 8;
constexpr int SLICE_W   = N_TOK / NSLICE_FB;
constexpr int CTS       = SLICE_W / BN;
constexpr int LDW       = BK + 8;
constexpr int NPART_FB  = NSLICE_FB * 2;

constexpr int FIN_BLOCKS = 256;

typedef __attribute__((ext_vector_type(4))) float f32x4;
typedef __attribute__((ext_vector_type(8))) short bf16x8;

__device__ __forceinline__ uint32_t pk2bf(float lo, float hi) {
    union { float f; uint32_t u; } a, b;
    a.f = lo; b.f = hi;
    uint32_t ua = (a.u + 0x7fffu + ((a.u >> 16) & 1u)) >> 16;
    uint32_t ub = (b.u + 0x7fffu + ((b.u >> 16) & 1u)) >> 16;
    return ua | (ub << 16);
}

__device__ __forceinline__ void async16(void* lds, const void* g) {
    __builtin_amdgcn_global_load_lds(
        (const __attribute__((address_space(1))) uint32_t*)g,
        (__attribute__((address_space(3))) uint32_t*)lds,
        16, 0, 0);
}

// ---------------------------------------------------------------------------
// Pass 1: fp32 -> bf16 pre-convert (once)
// ---------------------------------------------------------------------------
__global__ __launch_bounds__(256) void conv_bf16(
    const float* __restrict__ x, const float* __restrict__ e,
    ushort* __restrict__ xb, ushort* __restrict__ eb)
{
    constexpr int NCHUNK = N_TOK * D_DIM / 8;
    const int t0 = blockIdx.x * blockDim.x + threadIdx.x;
    const int stride = gridDim.x * blockDim.x;
    for (int c = t0; c < NCHUNK; c += stride) {
        float4 a0 = ((const float4*)x)[c * 2];
        float4 a1 = ((const float4*)x)[c * 2 + 1];
        uint4 p;
        p.x = pk2bf(a0.x, a0.y); p.y = pk2bf(a0.z, a0.w);
        p.z = pk2bf(a1.x, a1.y); p.w = pk2bf(a1.z, a1.w);
        ((uint4*)xb)[c] = p;

        float4 b0 = ((const float4*)e)[c * 2];
        float4 b1 = ((const float4*)e)[c * 2 + 1];
        uint4 q;
        q.x = pk2bf(b0.x, b0.y); q.y = pk2bf(b0.z, b0.w);
        q.z = pk2bf(b1.x, b1.y); q.w = pk2bf(b1.z, b1.w);
        ((uint4*)eb)[c] = q;
    }
}

// ---------------------------------------------------------------------------
// 8-phase staging helpers. LDS half-tile = [256][32] ushort (16 KB), 16B-slot
// swizzle: physical slot = logical slot ^ ((row>>1)&3)  (involution, both sides)
// ---------------------------------------------------------------------------
__device__ __forceinline__ void stage_half(
    ushort* __restrict__ dst, const ushort* __restrict__ src,
    int row_base, int kcol, int wid, int lane)
{
#pragma unroll
    for (int s = 0; s < 2; ++s) {
        const int q0  = wid * 128 + s * 64;   // wave-uniform first chunk
        const int q   = q0 + lane;            // this lane's 16B chunk (0..1023)
        const int row = q >> 2;               // 4 chunks per 32-ushort row
        const int sub = (q & 3) ^ ((row >> 1) & 3);   // pre-swizzled source
        async16(dst + (size_t)q0 * 8,
                src + (size_t)(row_base + row) * D_DIM + kcol + sub * 8);
    }
}

__device__ __forceinline__ bf16x8 read_frag(
    const ushort* __restrict__ t, int row, int lhi)
{
    const int slot = lhi ^ ((row >> 1) & 3);  // swizzled read
    return *(const bf16x8*)(t + row * 32 + slot * 8);
}

#define BAR   do { __builtin_amdgcn_s_barrier(); __builtin_amdgcn_sched_barrier(0); } while (0)
#define LGKM0 do { asm volatile("s_waitcnt lgkmcnt(0)" ::: "memory"); __builtin_amdgcn_sched_barrier(0); } while (0)

// ---------------------------------------------------------------------------
// Pass 2: 256x256 8-phase GEMM (counted vmcnt, setprio, swizzled LDS) + lse
// ---------------------------------------------------------------------------
__global__ __launch_bounds__(512, 2) void nce_gemm8(
    const ushort* __restrict__ xb,    // [N_TOK, D] bf16 keys
    const ushort* __restrict__ eb,    // [N_TOK, D] bf16 queries
    float* __restrict__ numer,
    float* __restrict__ pm,
    float* __restrict__ ps)
{
    __shared__ ushort As[2][2][256 * 32];   // [buf][khalf] 16KB each -> 64KB
    __shared__ ushort Bs[2][2][256 * 32];   // 64KB  (total 128KB)

    const int rb   = blockIdx.x;
    const int cs   = blockIdx.y;
    const int row0 = rb * BM2;
    const int col0 = cs * BM2;

    const int tid  = threadIdx.x;
    const int lane = tid & 63;
    const int wid  = tid >> 6;         // 0..7
    const int wr   = wid >> 2;         // 0..1  (M-warps)
    const int wc   = wid & 3;          // 0..3  (N-warps)
    const int l15  = lane & 15;
    const int lhi  = lane >> 4;        // 0..3

    f32x4 acc[8][4];
#pragma unroll
    for (int a = 0; a < 8; ++a)
#pragma unroll
        for (int b = 0; b < 4; ++b)
            acc[a][b] = f32x4{0.f, 0.f, 0.f, 0.f};

    // Prologue: stage K-tile 0 chunks in order A0,B0,A1,B1 (8 loads/wave)
    stage_half(As[0][0], eb, row0, 0,  wid, lane);
    stage_half(Bs[0][0], xb, col0, 0,  wid, lane);
    stage_half(As[0][1], eb, row0, 32, wid, lane);
    stage_half(Bs[0][1], xb, col0, 32, wid, lane);

    bf16x8 bq[4];                      // B frags held across 2 phases
    bf16x8 af[4];

#pragma unroll 1
    for (int kt = 0; kt < KT2; ++kt) {
        const int c  = kt & 1, n = c ^ 1;
        const int kn = (kt + 1) * 64;
        const bool pre = (kt < KT2 - 1);

        // ---- phase 0: khalf 0, m-half 0 ----
        asm volatile("s_waitcnt vmcnt(4)" ::: "memory");  // A0,B0(kt) landed
        BAR;
#pragma unroll
        for (int nf = 0; nf < 4; ++nf)
            bq[nf] = read_frag(Bs[c][0], wc * 64 + nf * 16 + l15, lhi);
#pragma unroll
        for (int mf = 0; mf < 4; ++mf)
            af[mf] = read_frag(As[c][0], wr * 128 + mf * 16 + l15, lhi);
        if (pre) stage_half(As[n][0], eb, row0, kn, wid, lane);
        LGKM0;
        __builtin_amdgcn_s_setprio(1);
#pragma unroll
        for (int mf = 0; mf < 4; ++mf)
#pragma unroll
            for (int nf = 0; nf < 4; ++nf)
                acc[mf][nf] = __builtin_amdgcn_mfma_f32_16x16x32_bf16(
                    af[mf], bq[nf], acc[mf][nf], 0, 0, 0);
        __builtin_amdgcn_s_setprio(0);

        // ---- phase 1: khalf 0, m-half 1 ----
        BAR;
#pragma unroll
        for (int mf = 0; mf < 4; ++mf)
            af[mf] = read_frag(As[c][0], wr * 128 + (4 + mf) * 16 + l15, lhi);
        if (pre) stage_half(Bs[n][0], xb, col0, kn, wid, lane);
        LGKM0;
        __builtin_amdgcn_s_setprio(1);
#pragma unroll
        for (int mf = 0; mf < 4; ++mf)
#pragma unroll
            for (int nf = 0; nf < 4; ++nf)
                acc[4 + mf][nf] = __builtin_amdgcn_mfma_f32_16x16x32_bf16(
                    af[mf], bq[nf], acc[4 + mf][nf], 0, 0, 0);
        __builtin_amdgcn_s_setprio(0);

        // ---- phase 2: khalf 1, m-half 0 ----
        if (pre) { asm volatile("s_waitcnt vmcnt(4)" ::: "memory"); }
        else     { asm volatile("s_waitcnt vmcnt(0)" ::: "memory"); }
        BAR;
#pragma unroll
        for (int nf = 0; nf < 4; ++nf)
            bq[nf] = read_frag(Bs[c][1], wc * 64 + nf * 16 + l15, lhi);
#pragma unroll
        for (int mf = 0; mf < 4; ++mf)
            af[mf] = read_frag(As[c][1], wr * 128 + mf * 16 + l15, lhi);
        if (pre) stage_half(As[n][1], eb, row0, kn + 32, wid, lane);
        LGKM0;
        __builtin_amdgcn_s_setprio(1);
#pragma unroll
        for (int mf = 0; mf < 4; ++mf)
#pragma unroll
            for (int nf = 0; nf < 4; ++nf)
                acc[mf][nf] = __builtin_amdgcn_mfma_f32_16x16x32_bf16(
                    af[mf], bq[nf], acc[mf][nf], 0, 0, 0);
        __builtin_amdgcn_s_setprio(0);

        // ---- phase 3: khalf 1, m-half 1 ----
        BAR;
#pragma unroll
        for (int mf = 0; mf < 4; ++mf)
            af[mf] = read_frag(As[c][1], wr * 128 + (4 + mf) * 16 + l15, lhi);
        if (pre) stage_half(Bs[n][1], xb, col0, kn + 32, wid, lane);
        LGKM0;
        __builtin_amdgcn_s_setprio(1);
#pragma unroll
        for (int mf = 0; mf < 4; ++mf)
#pragma unroll
            for (int nf = 0; nf < 4; ++nf)
                acc[4 + mf][nf] = __builtin_amdgcn_mfma_f32_16x16x32_bf16(
                    af[mf], bq[nf], acc[4 + mf][nf], 0, 0, 0);
        __builtin_amdgcn_s_setprio(0);
    }

    // Epilogue: diagonal + per-(mf,r) softmax partial + 16-lane butterfly
#pragma unroll
    for (int mf = 0; mf < 8; ++mf)
#pragma unroll
        for (int r = 0; r < 4; ++r) {
            const int row_g = row0 + wr * 128 + mf * 16 + lhi * 4 + r;
#pragma unroll
            for (int nf = 0; nf < 4; ++nf) {
                const int col_g = col0 + wc * 64 + nf * 16 + l15;
                if (row_g == col_g) numer[row_g] = acc[mf][nf][r];
            }
            const float v0 = acc[mf][0][r], v1 = acc[mf][1][r];
            const float v2 = acc[mf][2][r], v3 = acc[mf][3][r];
            float m = fmaxf(fmaxf(v0, v1), fmaxf(v2, v3));
            float s = __expf(v0 - m) + __expf(v1 - m)
                    + __expf(v2 - m) + __expf(v3 - m);
#pragma unroll
            for (int off = 1; off < 16; off <<= 1) {
                const float mo = __shfl_xor(m, off, 64);
                const float so = __shfl_xor(s, off, 64);
                const float mn = fmaxf(m, mo);
                s = s * __expf(m - mn) + so * __expf(mo - mn);
                m = mn;
            }
            if (l15 == 0) {
                pm[row_g * NPART + cs * 4 + wc] = m;
                ps[row_g * NPART + cs * 4 + wc] = s;
            }
        }
}

// ---------------------------------------------------------------------------
// Pass 3a: one WAVE per row — coalesced partial combine + masked row loss
// ---------------------------------------------------------------------------
__global__ __launch_bounds__(256) void nce_finish_a(
    const int* __restrict__ tgt,
    const float* __restrict__ numer,
    const float* __restrict__ pm,
    const float* __restrict__ ps,
    float* __restrict__ bl_loss,
    float* __restrict__ bl_cnt,
    int npart)
{
    const int tid  = threadIdx.x;
    const int lane = tid & 63;
    const int wv   = tid >> 6;
    const int waves_total = gridDim.x * 4;

    float loss = 0.f, cnt = 0.f;

    for (int row = blockIdx.x * 4 + wv; row < N_TOK; row += waves_total) {
        if (tgt[row] != MASK_ID_V) continue;
        float pmv = -3.0e38f, psv = 0.f;
        if (lane < npart) {
            pmv = pm[row * npart + lane];
            psv = ps[row * npart + lane];
        }
        float m = pmv;
#pragma unroll
        for (int off = 32; off; off >>= 1) m = fmaxf(m, __shfl_xor(m, off, 64));
        float sv = psv * __expf(pmv - m);
#pragma unroll
        for (int off = 32; off; off >>= 1) sv += __shfl_xor(sv, off, 64);
        if (lane == 0) {
            loss += numer[row] - (m + __logf(sv));
            cnt  += 1.f;
        }
    }

    __shared__ float sl[4], sc[4];
    if (lane == 0) { sl[wv] = loss; sc[wv] = cnt; }
    __syncthreads();
    if (tid == 0) {
        bl_loss[blockIdx.x] = sl[0] + sl[1] + sl[2] + sl[3];
        bl_cnt[blockIdx.x]  = sc[0] + sc[1] + sc[2] + sc[3];
    }
}

__global__ __launch_bounds__(256) void nce_finish_b(
    const float* __restrict__ bl_loss,
    const float* __restrict__ bl_cnt,
    float* __restrict__ out, int nblk)
{
    const int tid = threadIdx.x;
    float l = 0.f, c = 0.f;
    for (int i = tid; i < nblk; i += 256) { l += bl_loss[i]; c += bl_cnt[i]; }
    __shared__ float sl[256], sc[256];
    sl[tid] = l; sc[tid] = c;
    __syncthreads();
    for (int off = 128; off; off >>= 1) {
        if (tid < off) { sl[tid] += sl[tid + off]; sc[tid] += sc[tid + off]; }
        __syncthreads();
    }
    if (tid == 0) out[0] = -(sl[0] / sc[0]);
}

// ---------------------------------------------------------------------------
// Fallback (on-the-fly convert) — only if ws too small
// ---------------------------------------------------------------------------
__global__ __launch_bounds__(256, 2) void nce_gemm_fb(
    const float* __restrict__ x, const float* __restrict__ emb,
    float* __restrict__ numer, float* __restrict__ pm, float* __restrict__ ps)
{
    __shared__ ushort At[BM][LDW];
    __shared__ ushort Bt[BN][LDW];

    const int rb = blockIdx.x, cs = blockIdx.y;
    const int row0 = rb * BM, col0 = cs * SLICE_W;
    const int tid = threadIdx.x, lane = tid & 63, wid = tid >> 6;
    const int wr = wid >> 1, wc = wid & 1, l15 = lane & 15, lhi = lane >> 4;

    float m_run[16], s_run[16];
#pragma unroll
    for (int i = 0; i < 16; ++i) { m_run[i] = -3.0e38f; s_run[i] = 0.0f; }

    for (int ct = 0; ct < CTS; ++ct) {
        const int colt0 = col0 + ct * BN;
        f32x4 acc[4][4];
#pragma unroll
        for (int a = 0; a < 4; ++a)
#pragma unroll
            for (int b = 0; b < 4; ++b) acc[a][b] = f32x4{0.f,0.f,0.f,0.f};

#pragma unroll 1
        for (int kt = 0; kt < KST; ++kt) {
            __syncthreads();
#pragma unroll
            for (int i = 0; i < 4; ++i) {
                const int chunk = tid + i * 256;
                const int r = chunk >> 3, c8 = (chunk & 7) << 3;
                const float* ga = emb + (size_t)(row0 + r) * D_DIM + kt * BK + c8;
                float4 a0 = *(const float4*)(ga); float4 a1 = *(const float4*)(ga + 4);
                uint4 pa;
                pa.x = pk2bf(a0.x, a0.y); pa.y = pk2bf(a0.z, a0.w);
                pa.z = pk2bf(a1.x, a1.y); pa.w = pk2bf(a1.z, a1.w);
                *(uint4*)&At[r][c8] = pa;
                const float* gb = x + (size_t)(colt0 + r) * D_DIM + kt * BK + c8;
                float4 b0 = *(const float4*)(gb); float4 b1 = *(const float4*)(gb + 4);
                uint4 pb;
                pb.x = pk2bf(b0.x, b0.y); pb.y = pk2bf(b0.z, b0.w);
                pb.z = pk2bf(b1.x, b1.y); pb.w = pk2bf(b1.z, b1.w);
                *(uint4*)&Bt[r][c8] = pb;
            }
            __syncthreads();
#pragma unroll
            for (int kp = 0; kp < 2; ++kp) {
                const int ko = kp * 32 + lhi * 8;
                bf16x8 af[4], bfr[4];
#pragma unroll
                for (int mi = 0; mi < 4; ++mi)
                    af[mi] = *(const bf16x8*)&At[wr*64 + mi*16 + l15][ko];
#pragma unroll
                for (int ni = 0; ni < 4; ++ni)
                    bfr[ni] = *(const bf16x8*)&Bt[wc*64 + ni*16 + l15][ko];
#pragma unroll
                for (int mi = 0; mi < 4; ++mi)
#pragma unroll
                    for (int ni = 0; ni < 4; ++ni)
                        acc[mi][ni] = __builtin_amdgcn_mfma_f32_16x16x32_bf16(
                            af[mi], bfr[ni], acc[mi][ni], 0, 0, 0);
            }
        }

#pragma unroll
        for (int mi = 0; mi < 4; ++mi)
#pragma unroll
            for (int r = 0; r < 4; ++r) {
                const int row_g = row0 + wr*64 + mi*16 + lhi*4 + r;
#pragma unroll
                for (int ni = 0; ni < 4; ++ni) {
                    const int col_g = colt0 + wc*64 + ni*16 + l15;
                    if (row_g == col_g) numer[row_g] = acc[mi][ni][r];
                }
                const int idx = mi * 4 + r;
                const float v0 = acc[mi][0][r], v1 = acc[mi][1][r];
                const float v2 = acc[mi][2][r], v3 = acc[mi][3][r];
                const float mx = fmaxf(fmaxf(v0, v1), fmaxf(v2, v3));
                const float mn = fmaxf(m_run[idx], mx);
                const float scale = __expf(m_run[idx] - mn);
                s_run[idx] = s_run[idx] * scale
                           + __expf(v0 - mn) + __expf(v1 - mn)
                           + __expf(v2 - mn) + __expf(v3 - mn);
                m_run[idx] = mn;
            }
    }

#pragma unroll
    for (int idx = 0; idx < 16; ++idx) {
        float m = m_run[idx], s = s_run[idx];
#pragma unroll
        for (int off = 1; off < 16; off <<= 1) {
            const float mo = __shfl_xor(m, off, 64);
            const float so = __shfl_xor(s, off, 64);
            const float mn = fmaxf(m, mo);
            s = s * __expf(m - mn) + so * __expf(mo - mn);
            m = mn;
        }
        m_run[idx] = m; s_run[idx] = s;
    }

    if (l15 == 0) {
        const int slot = cs * 2 + wc;
#pragma unroll
        for (int mi = 0; mi < 4; ++mi)
#pragma unroll
            for (int r = 0; r < 4; ++r) {
                const int row_g = row0 + wr*64 + mi*16 + lhi*4 + r;
                pm[row_g * NPART_FB + slot] = m_run[mi*4 + r];
                ps[row_g * NPART_FB + slot] = s_run[mi*4 + r];
            }
    }
}

extern "C" void kernel_launch(void* const* d_in, const int* in_sizes, int n_in,
                              void* d_out, int out_size, void* d_ws, size_t ws_size,
                              hipStream_t stream) {
    (void)in_sizes; (void)n_in; (void)out_size;
    const float* x   = (const float*)d_in[0];
    const float* emb = (const float*)d_in[1];
    const int*   tgt = (const int*)d_in[2];
    float* out = (float*)d_out;

    const size_t elems = (size_t)N_TOK * D_DIM;
    const size_t need  = elems * 2 * 2
                       + (size_t)N_TOK * 4
                       + (size_t)N_TOK * NPART * 4 * 2
                       + FIN_BLOCKS * 8;

    if (ws_size >= need) {
        ushort* xb    = (ushort*)d_ws;
        ushort* eb    = xb + elems;
        float*  numer = (float*)(eb + elems);
        float*  pm    = numer + N_TOK;
        float*  ps    = pm + (size_t)N_TOK * NPART;
        float*  bl    = ps + (size_t)N_TOK * NPART;
        float*  bc    = bl + FIN_BLOCKS;

        conv_bf16<<<1024, 256, 0, stream>>>(x, emb, xb, eb);
        nce_gemm8<<<dim3(N_TOK / BM2, NSL2), 512, 0, stream>>>(xb, eb, numer, pm, ps);
        nce_finish_a<<<FIN_BLOCKS, 256, 0, stream>>>(tgt, numer, pm, ps, bl, bc, NPART);
        nce_finish_b<<<1, 256, 0, stream>>>(bl, bc, out, FIN_BLOCKS);
    } else {
        float* numer = (float*)d_ws;
        float* pm    = numer + N_TOK;
        float* ps    = pm + (size_t)N_TOK * NPART_FB;
        float* bl    = ps + (size_t)N_TOK * NPART_FB;
        float* bc    = bl + FIN_BLOCKS;
        nce_gemm_fb<<<dim3(N_TOK / BM, NSLICE_FB), 256, 0, stream>>>(x, emb, numer, pm, ps);
        nce_finish_a<<<FIN_BLOCKS, 256, 0, stream>>>(tgt, numer, pm, ps, bl, bc, NPART_FB);
        nce_finish_b<<<1, 256, 0, stream>>>(bl, bc, out, FIN_BLOCKS);
    }
}

// Round 6
// 54.801 us; speedup vs baseline: 2.7080x; 1.1009x over previous
//
#include <hip/hip_runtime.h>
#include <hip/hip_bf16.h>
#include <stdint.h>

// Problem constants (B=8, S=512, D=1024)
constexpr int N_TOK  = 4096;   // B*S
constexpr int D_DIM  = 1024;
constexpr int MASK_ID_V = 8192;

// Fast path: 256x256 tiles, 16 waves (4Mx4N), BK=64 as 2 halves of 32
constexpr int BM2  = 256;
constexpr int KT2  = D_DIM / 64;     // 16 K-tiles
constexpr int NSL2 = N_TOK / BM2;    // 16 col slices
constexpr int NPART = NSL2 * 4;      // 64 partials/row (4 wc-waves per slice)

// Fallback tiling (used only if ws too small)
constexpr int BM = 128, BN = 128, BK = 64;
constexpr int KST = D_DIM / BK;
constexpr int NSLICE_FB = 8;
constexpr int SLICE_W   = N_TOK / NSLICE_FB;
constexpr int CTS       = SLICE_W / BN;
constexpr int LDW       = BK + 8;
constexpr int NPART_FB  = NSLICE_FB * 2;

constexpr int FIN_BLOCKS = 256;

typedef __attribute__((ext_vector_type(4))) float f32x4;
typedef __attribute__((ext_vector_type(8))) short bf16x8;

__device__ __forceinline__ uint32_t pk2bf(float lo, float hi) {
    union { float f; uint32_t u; } a, b;
    a.f = lo; b.f = hi;
    uint32_t ua = (a.u + 0x7fffu + ((a.u >> 16) & 1u)) >> 16;
    uint32_t ub = (b.u + 0x7fffu + ((b.u >> 16) & 1u)) >> 16;
    return ua | (ub << 16);
}

__device__ __forceinline__ void async16(void* lds, const void* g) {
    __builtin_amdgcn_global_load_lds(
        (const __attribute__((address_space(1))) uint32_t*)g,
        (__attribute__((address_space(3))) uint32_t*)lds,
        16, 0, 0);
}

#define BAR   do { __builtin_amdgcn_s_barrier(); __builtin_amdgcn_sched_barrier(0); } while (0)
#define LGKM0 do { asm volatile("s_waitcnt lgkmcnt(0)" ::: "memory"); __builtin_amdgcn_sched_barrier(0); } while (0)

// ---------------------------------------------------------------------------
// Pass 1: fp32 -> bf16 pre-convert (once)
// ---------------------------------------------------------------------------
__global__ __launch_bounds__(256) void conv_bf16(
    const float* __restrict__ x, const float* __restrict__ e,
    ushort* __restrict__ xb, ushort* __restrict__ eb)
{
    constexpr int NCHUNK = N_TOK * D_DIM / 8;
    const int t0 = blockIdx.x * blockDim.x + threadIdx.x;
    const int stride = gridDim.x * blockDim.x;
    for (int c = t0; c < NCHUNK; c += stride) {
        float4 a0 = ((const float4*)x)[c * 2];
        float4 a1 = ((const float4*)x)[c * 2 + 1];
        uint4 p;
        p.x = pk2bf(a0.x, a0.y); p.y = pk2bf(a0.z, a0.w);
        p.z = pk2bf(a1.x, a1.y); p.w = pk2bf(a1.z, a1.w);
        ((uint4*)xb)[c] = p;

        float4 b0 = ((const float4*)e)[c * 2];
        float4 b1 = ((const float4*)e)[c * 2 + 1];
        uint4 q;
        q.x = pk2bf(b0.x, b0.y); q.y = pk2bf(b0.z, b0.w);
        q.z = pk2bf(b1.x, b1.y); q.w = pk2bf(b1.z, b1.w);
        ((uint4*)eb)[c] = q;
    }
}

// ---------------------------------------------------------------------------
// Pass 2: 256x256 GEMM, 16 waves, 2 phases/K-tile, counted vmcnt, swizzled LDS
// ---------------------------------------------------------------------------
__global__ __launch_bounds__(1024, 4) void nce_gemm8(
    const ushort* __restrict__ xb,    // [N_TOK, D] bf16 keys
    const ushort* __restrict__ eb,    // [N_TOK, D] bf16 queries
    float* __restrict__ numer,
    float* __restrict__ pm,
    float* __restrict__ ps)
{
    __shared__ ushort As[2][2][8192];   // [buf][khalf][256*32]  64 KB
    __shared__ ushort Bs[2][2][8192];   // 64 KB  (total 128 KB)

    // Bijective XCD-chunked swizzle: each XCD -> two 4x4 tile-chunks
    const int bid   = blockIdx.x;
    const int sw    = (bid & 7) * 32 + (bid >> 3);
    const int chunk = sw >> 4, win = sw & 15;
    const int rb    = (chunk & 3) * 4 + (win & 3);
    const int cs    = (chunk >> 2) * 4 + (win >> 2);
    const int row0  = rb * BM2;
    const int col0  = cs * BM2;

    const int tid  = threadIdx.x;
    const int lane = tid & 63;
    const int wid  = tid >> 6;         // 0..15
    const int wr   = wid >> 2;         // 0..3  (M-warps)
    const int wc   = wid & 3;          // 0..3  (N-warps)
    const int l15  = lane & 15;
    const int lhi  = lane >> 4;        // 0..3

    // Staging addresses (per lane, loop-invariant). LDS dest is linear;
    // source is pre-swizzled: phys 16B-slot = logical ^ ((row>>1)&3).
    const int srow = wid * 16 + (lane >> 2);
    const int ssub = (lane & 3) ^ ((srow >> 1) & 3);
    const ushort* gA = eb + (size_t)(row0 + srow) * D_DIM + ssub * 8;
    const ushort* gB = xb + (size_t)(col0 + srow) * D_DIM + ssub * 8;
    ushort* ldsA = &As[0][0][0] + wid * 512;   // wave-uniform base
    ushort* ldsB = &Bs[0][0][0] + wid * 512;

    // Frag read offsets (elems) — swizzle slot is mf/nf-independent
    const int arow = wr * 64 + l15;
    const int aoff = arow * 32 + (lhi ^ ((arow >> 1) & 3)) * 8;
    const int brow = wc * 64 + l15;
    const int boff = brow * 32 + (lhi ^ ((brow >> 1) & 3)) * 8;

    f32x4 acc[4][4];
#pragma unroll
    for (int a = 0; a < 4; ++a)
#pragma unroll
        for (int b = 0; b < 4; ++b)
            acc[a][b] = f32x4{0.f, 0.f, 0.f, 0.f};

    // Prologue: stage K-tile 0 (order A0,B0,A1,B1 -> vmcnt counting)
    async16(ldsA + 0 * 8192, gA);
    async16(ldsB + 0 * 8192, gB);
    async16(ldsA + 1 * 8192, gA + 32);
    async16(ldsB + 1 * 8192, gB + 32);
    const ushort* gAn = gA + 64;
    const ushort* gBn = gB + 64;

    bf16x8 af[4], bq[4];

#pragma unroll 1
    for (int kt = 0; kt < KT2; ++kt) {
        const int c = kt & 1, n = c ^ 1;
        const bool pre = (kt < KT2 - 1);

        // ---- phase 0: khalf 0 ----
        asm volatile("s_waitcnt vmcnt(2)" ::: "memory");   // A0,B0(kt) landed
        BAR;
        {
            const ushort* aB = &As[c][0][0] + aoff;
            const ushort* bB = &Bs[c][0][0] + boff;
#pragma unroll
            for (int i = 0; i < 4; ++i) {
                af[i] = *(const bf16x8*)(aB + i * 512);
                bq[i] = *(const bf16x8*)(bB + i * 512);
            }
        }
        if (pre) {
            async16(ldsA + (n * 2 + 0) * 8192, gAn);
            async16(ldsB + (n * 2 + 0) * 8192, gBn);
        }
        LGKM0;
        __builtin_amdgcn_s_setprio(1);
#pragma unroll
        for (int mf = 0; mf < 4; ++mf)
#pragma unroll
            for (int nf = 0; nf < 4; ++nf)
                acc[mf][nf] = __builtin_amdgcn_mfma_f32_16x16x32_bf16(
                    af[mf], bq[nf], acc[mf][nf], 0, 0, 0);
        __builtin_amdgcn_s_setprio(0);

        // ---- phase 1: khalf 1 ----
        if (pre) { asm volatile("s_waitcnt vmcnt(2)" ::: "memory"); }
        else     { asm volatile("s_waitcnt vmcnt(0)" ::: "memory"); }
        BAR;
        {
            const ushort* aB = &As[c][1][0] + aoff;
            const ushort* bB = &Bs[c][1][0] + boff;
#pragma unroll
            for (int i = 0; i < 4; ++i) {
                af[i] = *(const bf16x8*)(aB + i * 512);
                bq[i] = *(const bf16x8*)(bB + i * 512);
            }
        }
        if (pre) {
            async16(ldsA + (n * 2 + 1) * 8192, gAn + 32);
            async16(ldsB + (n * 2 + 1) * 8192, gBn + 32);
            gAn += 64; gBn += 64;
        }
        LGKM0;
        __builtin_amdgcn_s_setprio(1);
#pragma unroll
        for (int mf = 0; mf < 4; ++mf)
#pragma unroll
            for (int nf = 0; nf < 4; ++nf)
                acc[mf][nf] = __builtin_amdgcn_mfma_f32_16x16x32_bf16(
                    af[mf], bq[nf], acc[mf][nf], 0, 0, 0);
        __builtin_amdgcn_s_setprio(0);
    }

    // Epilogue: diagonal + per-(mf,r) softmax partial + 16-lane butterfly
#pragma unroll
    for (int mf = 0; mf < 4; ++mf)
#pragma unroll
        for (int r = 0; r < 4; ++r) {
            const int row_g = row0 + wr * 64 + mf * 16 + lhi * 4 + r;
#pragma unroll
            for (int nf = 0; nf < 4; ++nf) {
                const int col_g = col0 + wc * 64 + nf * 16 + l15;
                if (row_g == col_g) numer[row_g] = acc[mf][nf][r];
            }
            const float v0 = acc[mf][0][r], v1 = acc[mf][1][r];
            const float v2 = acc[mf][2][r], v3 = acc[mf][3][r];
            float m = fmaxf(fmaxf(v0, v1), fmaxf(v2, v3));
            float s = __expf(v0 - m) + __expf(v1 - m)
                    + __expf(v2 - m) + __expf(v3 - m);
#pragma unroll
            for (int off = 1; off < 16; off <<= 1) {
                const float mo = __shfl_xor(m, off, 64);
                const float so = __shfl_xor(s, off, 64);
                const float mn = fmaxf(m, mo);
                s = s * __expf(m - mn) + so * __expf(mo - mn);
                m = mn;
            }
            if (l15 == 0) {
                pm[row_g * NPART + cs * 4 + wc] = m;
                ps[row_g * NPART + cs * 4 + wc] = s;
            }
        }
}

// ---------------------------------------------------------------------------
// Pass 3a: one WAVE per row — coalesced partial combine + masked row loss
// ---------------------------------------------------------------------------
__global__ __launch_bounds__(256) void nce_finish_a(
    const int* __restrict__ tgt,
    const float* __restrict__ numer,
    const float* __restrict__ pm,
    const float* __restrict__ ps,
    float* __restrict__ bl_loss,
    float* __restrict__ bl_cnt,
    int npart)
{
    const int tid  = threadIdx.x;
    const int lane = tid & 63;
    const int wv   = tid >> 6;
    const int waves_total = gridDim.x * 4;

    float loss = 0.f, cnt = 0.f;

    for (int row = blockIdx.x * 4 + wv; row < N_TOK; row += waves_total) {
        if (tgt[row] != MASK_ID_V) continue;
        float pmv = -3.0e38f, psv = 0.f;
        if (lane < npart) {
            pmv = pm[row * npart + lane];
            psv = ps[row * npart + lane];
        }
        float m = pmv;
#pragma unroll
        for (int off = 32; off; off >>= 1) m = fmaxf(m, __shfl_xor(m, off, 64));
        float sv = psv * __expf(pmv - m);
#pragma unroll
        for (int off = 32; off; off >>= 1) sv += __shfl_xor(sv, off, 64);
        if (lane == 0) {
            loss += numer[row] - (m + __logf(sv));
            cnt  += 1.f;
        }
    }

    __shared__ float sl[4], sc[4];
    if (lane == 0) { sl[wv] = loss; sc[wv] = cnt; }
    __syncthreads();
    if (tid == 0) {
        bl_loss[blockIdx.x] = sl[0] + sl[1] + sl[2] + sl[3];
        bl_cnt[blockIdx.x]  = sc[0] + sc[1] + sc[2] + sc[3];
    }
}

__global__ __launch_bounds__(256) void nce_finish_b(
    const float* __restrict__ bl_loss,
    const float* __restrict__ bl_cnt,
    float* __restrict__ out, int nblk)
{
    const int tid = threadIdx.x;
    float l = 0.f, c = 0.f;
    for (int i = tid; i < nblk; i += 256) { l += bl_loss[i]; c += bl_cnt[i]; }
    __shared__ float sl[256], sc[256];
    sl[tid] = l; sc[tid] = c;
    __syncthreads();
    for (int off = 128; off; off >>= 1) {
        if (tid < off) { sl[tid] += sl[tid + off]; sc[tid] += sc[tid + off]; }
        __syncthreads();
    }
    if (tid == 0) out[0] = -(sl[0] / sc[0]);
}

// ---------------------------------------------------------------------------
// Fallback (on-the-fly convert) — only if ws too small
// ---------------------------------------------------------------------------
__global__ __launch_bounds__(256, 2) void nce_gemm_fb(
    const float* __restrict__ x, const float* __restrict__ emb,
    float* __restrict__ numer, float* __restrict__ pm, float* __restrict__ ps)
{
    __shared__ ushort At[BM][LDW];
    __shared__ ushort Bt[BN][LDW];

    const int rb = blockIdx.x, cs = blockIdx.y;
    const int row0 = rb * BM, col0 = cs * SLICE_W;
    const int tid = threadIdx.x, lane = tid & 63, wid = tid >> 6;
    const int wr = wid >> 1, wc = wid & 1, l15 = lane & 15, lhi = lane >> 4;

    float m_run[16], s_run[16];
#pragma unroll
    for (int i = 0; i < 16; ++i) { m_run[i] = -3.0e38f; s_run[i] = 0.0f; }

    for (int ct = 0; ct < CTS; ++ct) {
        const int colt0 = col0 + ct * BN;
        f32x4 acc[4][4];
#pragma unroll
        for (int a = 0; a < 4; ++a)
#pragma unroll
            for (int b = 0; b < 4; ++b) acc[a][b] = f32x4{0.f,0.f,0.f,0.f};

#pragma unroll 1
        for (int kt = 0; kt < KST; ++kt) {
            __syncthreads();
#pragma unroll
            for (int i = 0; i < 4; ++i) {
                const int chunk = tid + i * 256;
                const int r = chunk >> 3, c8 = (chunk & 7) << 3;
                const float* ga = emb + (size_t)(row0 + r) * D_DIM + kt * BK + c8;
                float4 a0 = *(const float4*)(ga); float4 a1 = *(const float4*)(ga + 4);
                uint4 pa;
                pa.x = pk2bf(a0.x, a0.y); pa.y = pk2bf(a0.z, a0.w);
                pa.z = pk2bf(a1.x, a1.y); pa.w = pk2bf(a1.z, a1.w);
                *(uint4*)&At[r][c8] = pa;
                const float* gb = x + (size_t)(colt0 + r) * D_DIM + kt * BK + c8;
                float4 b0 = *(const float4*)(gb); float4 b1 = *(const float4*)(gb + 4);
                uint4 pb;
                pb.x = pk2bf(b0.x, b0.y); pb.y = pk2bf(b0.z, b0.w);
                pb.z = pk2bf(b1.x, b1.y); pb.w = pk2bf(b1.z, b1.w);
                *(uint4*)&Bt[r][c8] = pb;
            }
            __syncthreads();
#pragma unroll
            for (int kp = 0; kp < 2; ++kp) {
                const int ko = kp * 32 + lhi * 8;
                bf16x8 af[4], bfr[4];
#pragma unroll
                for (int mi = 0; mi < 4; ++mi)
                    af[mi] = *(const bf16x8*)&At[wr*64 + mi*16 + l15][ko];
#pragma unroll
                for (int ni = 0; ni < 4; ++ni)
                    bfr[ni] = *(const bf16x8*)&Bt[wc*64 + ni*16 + l15][ko];
#pragma unroll
                for (int mi = 0; mi < 4; ++mi)
#pragma unroll
                    for (int ni = 0; ni < 4; ++ni)
                        acc[mi][ni] = __builtin_amdgcn_mfma_f32_16x16x32_bf16(
                            af[mi], bfr[ni], acc[mi][ni], 0, 0, 0);
            }
        }

#pragma unroll
        for (int mi = 0; mi < 4; ++mi)
#pragma unroll
            for (int r = 0; r < 4; ++r) {
                const int row_g = row0 + wr*64 + mi*16 + lhi*4 + r;
#pragma unroll
                for (int ni = 0; ni < 4; ++ni) {
                    const int col_g = colt0 + wc*64 + ni*16 + l15;
                    if (row_g == col_g) numer[row_g] = acc[mi][ni][r];
                }
                const int idx = mi * 4 + r;
                const float v0 = acc[mi][0][r], v1 = acc[mi][1][r];
                const float v2 = acc[mi][2][r], v3 = acc[mi][3][r];
                const float mx = fmaxf(fmaxf(v0, v1), fmaxf(v2, v3));
                const float mn = fmaxf(m_run[idx], mx);
                const float scale = __expf(m_run[idx] - mn);
                s_run[idx] = s_run[idx] * scale
                           + __expf(v0 - mn) + __expf(v1 - mn)
                           + __expf(v2 - mn) + __expf(v3 - mn);
                m_run[idx] = mn;
            }
    }

#pragma unroll
    for (int idx = 0; idx < 16; ++idx) {
        float m = m_run[idx], s = s_run[idx];
#pragma unroll
        for (int off = 1; off < 16; off <<= 1) {
            const float mo = __shfl_xor(m, off, 64);
            const float so = __shfl_xor(s, off, 64);
            const float mn = fmaxf(m, mo);
            s = s * __expf(m - mn) + so * __expf(mo - mn);
            m = mn;
        }
        m_run[idx] = m; s_run[idx] = s;
    }

    if (l15 == 0) {
        const int slot = cs * 2 + wc;
#pragma unroll
        for (int mi = 0; mi < 4; ++mi)
#pragma unroll
            for (int r = 0; r < 4; ++r) {
                const int row_g = row0 + wr*64 + mi*16 + lhi*4 + r;
                pm[row_g * NPART_FB + slot] = m_run[mi*4 + r];
                ps[row_g * NPART_FB + slot] = s_run[mi*4 + r];
            }
    }
}

extern "C" void kernel_launch(void* const* d_in, const int* in_sizes, int n_in,
                              void* d_out, int out_size, void* d_ws, size_t ws_size,
                              hipStream_t stream) {
    (void)in_sizes; (void)n_in; (void)out_size;
    const float* x   = (const float*)d_in[0];
    const float* emb = (const float*)d_in[1];
    const int*   tgt = (const int*)d_in[2];
    float* out = (float*)d_out;

    const size_t elems = (size_t)N_TOK * D_DIM;
    const size_t need  = elems * 2 * 2
                       + (size_t)N_TOK * 4
                       + (size_t)N_TOK * NPART * 4 * 2
                       + FIN_BLOCKS * 8;

    if (ws_size >= need) {
        ushort* xb    = (ushort*)d_ws;
        ushort* eb    = xb + elems;
        float*  numer = (float*)(eb + elems);
        float*  pm    = numer + N_TOK;
        float*  ps    = pm + (size_t)N_TOK * NPART;
        float*  bl    = ps + (size_t)N_TOK * NPART;
        float*  bc    = bl + FIN_BLOCKS;

        conv_bf16<<<1024, 256, 0, stream>>>(x, emb, xb, eb);
        nce_gemm8<<<NSL2 * NSL2, 1024, 0, stream>>>(xb, eb, numer, pm, ps);
        nce_finish_a<<<FIN_BLOCKS, 256, 0, stream>>>(tgt, numer, pm, ps, bl, bc, NPART);
        nce_finish_b<<<1, 256, 0, stream>>>(bl, bc, out, FIN_BLOCKS);
    } else {
        float* numer = (float*)d_ws;
        float* pm    = numer + N_TOK;
        float* ps    = pm + (size_t)N_TOK * NPART_FB;
        float* bl    = ps + (size_t)N_TOK * NPART_FB;
        float* bc    = bl + FIN_BLOCKS;
        nce_gemm_fb<<<dim3(N_TOK / BM, NSLICE_FB), 256, 0, stream>>>(x, emb, numer, pm, ps);
        nce_finish_a<<<FIN_BLOCKS, 256, 0, stream>>>(tgt, numer, pm, ps, bl, bc, NPART_FB);
        nce_finish_b<<<1, 256, 0, stream>>>(bl, bc, out, FIN_BLOCKS);
    }
}